// Round 26
// baseline (115.420 us; speedup 1.0000x reference)
//
#include <hip/hip_runtime.h>
#include <hip/hip_bf16.h>
#include <stdint.h>

typedef unsigned short u16;
typedef __attribute__((ext_vector_type(8))) short bf16x8;
typedef __attribute__((ext_vector_type(4))) float f32x4;

#define AS1 __attribute__((address_space(1)))
#define AS3 __attribute__((address_space(3)))

__device__ __forceinline__ void gload_lds16(const void* g, void* l) {
  __builtin_amdgcn_global_load_lds((const AS1 void*)g, (AS3 void*)l, 16, 0, 0);
}

__device__ __forceinline__ u16 f2bf(float f) {
  union { float f; uint32_t u; } v; v.f = f;
  uint32_t r = v.u + 0x7FFFu + ((v.u >> 16) & 1u);
  return (u16)(r >> 16);
}

// ---------------- fp32 -> bf16, all five tensors in ONE launch ----------------
__global__ void cvt_all(const float* __restrict__ x,
                        const float* __restrict__ w0, const float* __restrict__ w1,
                        const float* __restrict__ w2, const float* __restrict__ w3,
                        u16* __restrict__ x16, u16* __restrict__ w16) {
  int i = blockIdx.x * 256 + threadIdx.x;          // float4 index
  const float* src; u16* dst; int off;
  if (i < 1048576) { src = x; dst = x16; off = i; }
  else {
    int j = i - 1048576; int w = j >> 18; off = j & 262143;
    src = (w == 0) ? w0 : (w == 1) ? w1 : (w == 2) ? w2 : w3;
    dst = w16 + (size_t)w * 1048576;
  }
  float4 v = ((const float4*)src)[off];
  uint64_t pk = (uint64_t)f2bf(v.x) | ((uint64_t)f2bf(v.y) << 16) |
                ((uint64_t)f2bf(v.z) << 32) | ((uint64_t)f2bf(v.w) << 48);
  ((uint64_t*)dst)[off] = pk;
}

// ---------------- B^T GEMM: C[m][n] = sum_k A[m][k]*Bw[n][k] + bias[n] ----------------
// BK=64, DOUBLE-buffered + counted vmcnt(8) (R24 ledger) COMPOSED with the
// R25-verified both-sides XOR swizzle (R24's regression carried 10.7M
// bank-conflict cycles that serialized compute; with conflicts fixed the
// prefetch has MFMA to hide under). 1-D grid, bijective XCD swizzle (T1).
// MODE 0: bf16 out; z<2 scatter to (B,H,T,d) via LDS-batched 16B stores
//         (Q scaled 0.125); z==2 writes V transposed to (B,H,d,T) via LDS.
// MODE 1: fp32 out, linear [m][n].
#define BM 128
#define BN 128

template<int MODE>
__global__ __launch_bounds__(256, 2)
void gemm_bt(const u16* __restrict__ A, const u16* __restrict__ Bw,
             const float* __restrict__ bias0, const float* __restrict__ bias1,
             const float* __restrict__ bias2, void* __restrict__ Out,
             u16* __restrict__ VtOut, int M, int N, int K)
{
  __shared__ __align__(16) u16 As[2][BM * 64];
  __shared__ __align__(16) u16 Bs[2][BN * 64];
  const int tid = threadIdx.x;
  const int lane = tid & 63, wid = tid >> 6;
  const int lr = lane & 15, lg = lane >> 4;
  const int id = blockIdx.x;
  const int cpx = gridDim.x >> 3;
  const int swz = (id & 7) * cpx + (id >> 3);
  const int z = swz >> 8;                       // 256 tiles per z-slice
  const int rem = swz & 255;
  const int m0 = (rem >> 3) * BM, n0 = (rem & 7) * BN;
  const u16* Bz = Bw + (size_t)z * N * K;
  const float* bias = (MODE == 0) ? (z == 0 ? bias0 : (z == 1 ? bias1 : bias2)) : bias0;
  const int wm = (wid >> 1) * 64, wn = (wid & 1) * 64;
  const int xsl = lr & 7;                       // fragment-read XOR
  const int nit = K >> 6;                       // 64-wide K tiles

#define STAGE(it, buf) do {                                                     \
    int kt_ = (it) * 64;                                                        \
    _Pragma("unroll")                                                           \
    for (int i_ = 0; i_ < 4; ++i_) {                                            \
      int cb_ = (i_ * 4 + wid) * 64;                                            \
      int c_ = cb_ + lane;                                                      \
      int row2_ = c_ >> 3;                                                      \
      int kc_ = ((c_ & 7) ^ (row2_ & 7)) * 8;   /* pre-swizzled source chunk */ \
      gload_lds16(A  + (size_t)(m0 + row2_) * K + kt_ + kc_,                    \
                  (void*)&As[buf][(size_t)cb_ * 8]);                            \
      gload_lds16(Bz + (size_t)(n0 + row2_) * K + kt_ + kc_,                    \
                  (void*)&Bs[buf][(size_t)cb_ * 8]);                            \
    }                                                                           \
  } while (0)

  f32x4 acc[4][4] = {};

  STAGE(0, 0);
  STAGE(1, 1);

  for (int it = 0; it < nit; ++it) {
    if (it + 1 < nit) asm volatile("s_waitcnt vmcnt(8)" ::: "memory");
    else              asm volatile("s_waitcnt vmcnt(0)" ::: "memory");
    __builtin_amdgcn_s_barrier();                // tile `it` resident for all

    const u16* Ab = &As[it & 1][0];
    const u16* Bb = &Bs[it & 1][0];
#pragma unroll
    for (int s = 0; s < 2; ++s) {
      bf16x8 af[4], bfr[4];
#pragma unroll
      for (int mf = 0; mf < 4; ++mf)
        af[mf]  = *(const bf16x8*)&Ab[(wm + mf * 16 + lr) * 64 + (((s * 4 + lg) ^ xsl) * 8)];
#pragma unroll
      for (int nf = 0; nf < 4; ++nf)
        bfr[nf] = *(const bf16x8*)&Bb[(wn + nf * 16 + lr) * 64 + (((s * 4 + lg) ^ xsl) * 8)];
#pragma unroll
      for (int mf = 0; mf < 4; ++mf)
#pragma unroll
        for (int nf = 0; nf < 4; ++nf)
          acc[mf][nf] = __builtin_amdgcn_mfma_f32_16x16x32_bf16(af[mf], bfr[nf], acc[mf][nf], 0, 0, 0);
    }

    asm volatile("s_waitcnt lgkmcnt(0)" ::: "memory");   // my LDS reads retired
    __builtin_amdgcn_s_barrier();                        // buffer free everywhere
    if (it + 2 < nit) STAGE(it + 2, it & 1);             // flies under next compute
  }
#undef STAGE

  if (MODE == 0) {
    __syncthreads();                       // all LDS activity done
    u16* tb = &As[0][0] + wid * 4096;      // 8 KB per wave (LDS dead now)
    if (z == 2) {
      // V epilogue: transpose 64x64 wave quadrant, store (B,H,d,T).
#pragma unroll
      for (int nf = 0; nf < 4; ++nf) {
        float bv = bias[n0 + wn + nf * 16 + lr];
#pragma unroll
        for (int mf = 0; mf < 4; ++mf)
#pragma unroll
          for (int r = 0; r < 4; ++r)
            tb[(nf * 16 + lr) * 64 + (mf * 16 + lg * 4 + r)] = f2bf(acc[mf][nf][r] + bv);
      }
      asm volatile("s_waitcnt lgkmcnt(0)" ::: "memory");  // own-wave writes only
#pragma unroll
      for (int c = 0; c < 8; ++c) {
        int nl = c * 8 + (lane >> 3);        // wave-local n (= d bits)
        int mc = lane & 7;                   // 8-elem m chunk
        bf16x8 vv = *(const bf16x8*)&tb[nl * 64 + mc * 8];
        int ng = n0 + wn + nl;               // global n -> (h,d)
        int mg = m0 + wm + mc * 8;           // global m -> (b,t)
        size_t addr = (((size_t)(mg >> 11) * 16 + (ng >> 6)) * 64 + (ng & 63)) * 2048 + (mg & 2047);
        *(bf16x8*)&VtOut[addr] = vv;
      }
    } else {
      // Q/K epilogue: LDS-batched, d-contiguous 16B stores to (B,H,T,d).
      float qs = (z == 0) ? 0.125f : 1.0f;   // fold 1/sqrt(d) into Q
#pragma unroll
      for (int nf = 0; nf < 4; ++nf) {
        float bv = bias[n0 + wn + nf * 16 + lr];
#pragma unroll
        for (int mf = 0; mf < 4; ++mf)
#pragma unroll
          for (int r = 0; r < 4; ++r)
            tb[(mf * 16 + lg * 4 + r) * 64 + nf * 16 + lr] = f2bf((acc[mf][nf][r] + bv) * qs);
      }
      asm volatile("s_waitcnt lgkmcnt(0)" ::: "memory");  // own-wave writes only
      u16* Oz = (u16*)Out + (size_t)z * 4194304;
#pragma unroll
      for (int c = 0; c < 8; ++c) {
        int ml = c * 8 + (lane >> 3);        // wave-local m
        int nc = lane & 7;                   // 8-elem n (d) chunk
        bf16x8 vv = *(const bf16x8*)&tb[ml * 64 + nc * 8];
        int mg = m0 + wm + ml;               // global m -> (b,t)
        int ng = n0 + wn + nc * 8;           // global n -> (h,d), 8-aligned
        size_t addr = ((size_t)(mg >> 11) * 16 + (ng >> 6)) * (size_t)(2048 * 64)
                    + (size_t)(mg & 2047) * 64 + (ng & 63);
        *(bf16x8*)&Oz[addr] = vv;
      }
    }
    return;
  }

#pragma unroll
  for (int nf = 0; nf < 4; ++nf) {
    float bv = bias[n0 + wn + nf * 16 + lr];
#pragma unroll
    for (int mf = 0; mf < 4; ++mf)
#pragma unroll
      for (int r = 0; r < 4; ++r) {
        int m = m0 + wm + mf * 16 + lg * 4 + r;
        int n = n0 + wn + nf * 16 + lr;
        ((float*)Out)[(size_t)m * N + n] = acc[mf][nf][r] + bv;
      }
  }
}

// ---------------- causal flash attention (R13 exact: best measured 46.5us) ----------------
// grid (16, B*H), 512 thr = 8 waves; block owns 128 q-rows (wave: 16);
// 128-key tiles. Single-buffer LDS + T14 async reg staging; raw barriers.
// Known tradeoff: compiler allocates 64 VGPR and spills ~16 MB/dispatch,
// but beats all clean-allocation variants (R11 54.1, R16 78.2, R18 52.2,
// R19 49.9). expf softmax + manual f2bf.
__global__ __launch_bounds__(512, 4)
void attn_fwd(const u16* __restrict__ q, const u16* __restrict__ k,
              const u16* __restrict__ vt, u16* __restrict__ y)
{
  __shared__ __align__(16) u16 Ks[128 * 64];     // [s][d]  slot = chunk ^ (s&7)
  __shared__ __align__(16) u16 Vs[64 * 128];     // [d][s]  slot = chunk ^ (d&7)
  __shared__ __align__(16) u16 Ps[8][16 * 136];  // per-wave P tile (pad 8)
  const int tid = threadIdx.x, lane = tid & 63, wid = tid >> 6;   // wid 0..7
  const int lr = lane & 15, lg = lane >> 4;
  const int bx = blockIdx.x, by = blockIdx.y;
  const int r4 = (bx + by) & 15;
  const int qt = (by & 16) ? r4 : 15 - r4;       // complementary-pair LPT
  const int q0 = qt * 128;
  const int bh = by;
  const u16* qg = q + (size_t)bh * 2048 * 64;
  const u16* kg = k + (size_t)bh * 2048 * 64;
  const u16* vg = vt + (size_t)bh * 64 * 2048;
  const int trow0 = q0 + wid * 16;
  const int tq = trow0 + lr;

  bf16x8 qa[2];                                   // Q pre-scaled by 0.125 in GEMM
#pragma unroll
  for (int kk = 0; kk < 2; ++kk)
    qa[kk] = *(const bf16x8*)&qg[(size_t)(trow0 + lr) * 64 + kk * 32 + lg * 8];

  // staging split across 8 waves:
  //  K: rows kr0=wid*16+l8 (+8), chunk s8 of 8   -> 2 loads
  //  V: row  vd =wid*8+l8, chunks s8, s8+8 of 16 -> 2 loads
  const int l8 = lane >> 3, s8 = lane & 7;
  const int kr0 = wid * 16 + l8;
  const int vd  = wid * 8 + l8;
  const u16* kld = kg + (size_t)kr0 * 64 + s8 * 8;
  const u16* vld = vg + (size_t)vd * 2048 + s8 * 8;
  u16* kst0 = &Ks[kr0 * 64 + (s8 ^ l8) * 8];           // (kr0+8)&7 == l8 too
  u16* kst1 = &Ks[(kr0 + 8) * 64 + (s8 ^ l8) * 8];
  u16* vst0 = &Vs[vd * 128 + ((s8    ) ^ (vd & 7)) * 8];
  u16* vst1 = &Vs[vd * 128 + ((s8 + 8) ^ (vd & 7)) * 8];

  bf16x8 ldK0, ldK1, ldV0, ldV1;
  ldK0 = *(const bf16x8*)(kld);
  ldK1 = *(const bf16x8*)(kld + 8 * 64);
  ldV0 = *(const bf16x8*)(vld);
  ldV1 = *(const bf16x8*)(vld + 64);

  f32x4 oacc[4] = {};
  float mrun = -1e30f, lrun = 0.f;
  const int nk2 = qt + 1;
  const int xsl = lr & 7;

  for (int j = 0; j < nk2; ++j) {
    // staged regs -> LDS (swizzled), then prefetch next tile
    *(bf16x8*)kst0 = ldK0;  *(bf16x8*)kst1 = ldK1;
    *(bf16x8*)vst0 = ldV0;  *(bf16x8*)vst1 = ldV1;
    if (j + 1 < nk2) {
      const u16* kn = kld + (size_t)(j + 1) * 8192;    // +128 rows
      const u16* vn = vld + (size_t)(j + 1) * 128;     // +128 cols
      ldK0 = *(const bf16x8*)(kn);
      ldK1 = *(const bf16x8*)(kn + 8 * 64);
      ldV0 = *(const bf16x8*)(vn);
      ldV1 = *(const bf16x8*)(vn + 64);
    }
    asm volatile("s_waitcnt lgkmcnt(0)" ::: "memory");   // my ds_writes done
    __builtin_amdgcn_s_barrier();                        // tile visible to all

    // QK^T swapped: sacc[sf][r] = S[s=j*128+sf*16+lg*4+r][t=tq]
    // kb half-batches of 4 keep peak live VGPRs moderate
    f32x4 sacc[8] = {};
#pragma unroll
    for (int kk = 0; kk < 2; ++kk) {
#pragma unroll
      for (int h = 0; h < 2; ++h) {
        bf16x8 kb[4];
#pragma unroll
        for (int sf = 0; sf < 4; ++sf)
          kb[sf] = *(const bf16x8*)&Ks[((h * 4 + sf) * 16 + lr) * 64 + (((kk * 4 + lg) ^ xsl) * 8)];
#pragma unroll
        for (int sf = 0; sf < 4; ++sf)
          sacc[h * 4 + sf] = __builtin_amdgcn_mfma_f32_16x16x32_bf16(kb[sf], qa[kk], sacc[h * 4 + sf], 0, 0, 0);
      }
    }

    if (j == qt) {                      // diagonal tile: mask s > t
#pragma unroll
      for (int sf = 0; sf < 8; ++sf)
#pragma unroll
        for (int r = 0; r < 4; ++r) {
          int s = j * 128 + sf * 16 + lg * 4 + r;
          if (s > tq) sacc[sf][r] = -1e30f;
        }
    }

    // online softmax for row tq: in-register tree max + 2-step lg reduce
    float m01 = fmaxf(fmaxf(fmaxf(sacc[0][0], sacc[0][1]), fmaxf(sacc[0][2], sacc[0][3])),
                      fmaxf(fmaxf(sacc[1][0], sacc[1][1]), fmaxf(sacc[1][2], sacc[1][3])));
    float m23 = fmaxf(fmaxf(fmaxf(sacc[2][0], sacc[2][1]), fmaxf(sacc[2][2], sacc[2][3])),
                      fmaxf(fmaxf(sacc[3][0], sacc[3][1]), fmaxf(sacc[3][2], sacc[3][3])));
    float m45 = fmaxf(fmaxf(fmaxf(sacc[4][0], sacc[4][1]), fmaxf(sacc[4][2], sacc[4][3])),
                      fmaxf(fmaxf(sacc[5][0], sacc[5][1]), fmaxf(sacc[5][2], sacc[5][3])));
    float m67 = fmaxf(fmaxf(fmaxf(sacc[6][0], sacc[6][1]), fmaxf(sacc[6][2], sacc[6][3])),
                      fmaxf(fmaxf(sacc[7][0], sacc[7][1]), fmaxf(sacc[7][2], sacc[7][3])));
    float mx = fmaxf(fmaxf(m01, m23), fmaxf(m45, m67));
    mx = fmaxf(mx, __shfl_xor(mx, 16));
    mx = fmaxf(mx, __shfl_xor(mx, 32));
    if (!__all(mx - mrun <= 8.0f)) {    // T13: rescale only when max moved
      float mn = fmaxf(mrun, mx);
      float scn = __expf(mrun - mn);
      mrun = mn;
      lrun *= scn;
      float scr[4];
#pragma unroll
      for (int r = 0; r < 4; ++r) scr[r] = __shfl(scn, lg * 4 + r);
#pragma unroll
      for (int nf = 0; nf < 4; ++nf)
#pragma unroll
        for (int r = 0; r < 4; ++r) oacc[nf][r] *= scr[r];
    }
    float rs = 0.f;
#pragma unroll
    for (int sf = 0; sf < 8; ++sf)
#pragma unroll
      for (int r = 0; r < 4; ++r) {
        float p = __expf(sacc[sf][r] - mrun);
        sacc[sf][r] = p;
        rs += p;
      }
    rs += __shfl_xor(rs, 16);
    rs += __shfl_xor(rs, 32);
    lrun += rs;

    // P -> LDS (wave-private): row t=lr, cols sf*16+lg*4+{0..3}
#pragma unroll
    for (int sf = 0; sf < 8; ++sf) {
      union { ushort4 u; uint2 d; } pk_;
      pk_.u.x = f2bf(sacc[sf][0]); pk_.u.y = f2bf(sacc[sf][1]);
      pk_.u.z = f2bf(sacc[sf][2]); pk_.u.w = f2bf(sacc[sf][3]);
      *(uint2*)&Ps[wid][lr * 136 + sf * 16 + lg * 4] = pk_.d;
    }

    // PV: O[t][n] += P[t][s] * Vt[n][s], s over 128 keys (kk 0..3)
#pragma unroll
    for (int kk = 0; kk < 4; ++kk) {
      bf16x8 pa = *(const bf16x8*)&Ps[wid][lr * 136 + kk * 32 + lg * 8];
      bf16x8 vb[4];
#pragma unroll
      for (int nf = 0; nf < 4; ++nf)
        vb[nf] = *(const bf16x8*)&Vs[(nf * 16 + lr) * 128 + (((kk * 4 + lg) ^ xsl) * 8)];
#pragma unroll
      for (int nf = 0; nf < 4; ++nf)
        oacc[nf] = __builtin_amdgcn_mfma_f32_16x16x32_bf16(pa, vb[nf], oacc[nf], 0, 0, 0);
    }

    asm volatile("s_waitcnt lgkmcnt(0)" ::: "memory");   // my K/V reads retired
    __builtin_amdgcn_s_barrier();                        // safe to overwrite
  }

  const int b = bh >> 4, h = bh & 15;
#pragma unroll
  for (int r = 0; r < 4; ++r) {
    float lshf = __shfl(lrun, lg * 4 + r);
    float inv = 1.f / lshf;
    int t = trow0 + lg * 4 + r;
#pragma unroll
    for (int nf = 0; nf < 4; ++nf) {
      int n = nf * 16 + lr;
      y[((size_t)b * 2048 + t) * 1024 + h * 64 + n] = f2bf(oacc[nf][r] * inv);
    }
  }
}

extern "C" void kernel_launch(void* const* d_in, const int* in_sizes, int n_in,
                              void* d_out, int out_size, void* d_ws, size_t ws_size,
                              hipStream_t stream) {
  const float* x  = (const float*)d_in[0];
  const float* Wq = (const float*)d_in[1];
  const float* bq = (const float*)d_in[2];
  const float* Wk = (const float*)d_in[3];
  const float* bk = (const float*)d_in[4];
  const float* Wv = (const float*)d_in[5];
  const float* bv = (const float*)d_in[6];
  const float* Wp = (const float*)d_in[7];
  const float* bp = (const float*)d_in[8];

  char* ws = (char*)d_ws;
  u16* x16  = (u16*)(ws + (size_t)0);          // 4096x1024 bf16 (reused as y16 later)
  u16* w16  = (u16*)(ws + ((size_t)8  << 20)); // Wq,Wk,Wv,Wp bf16, 1M elems each
  u16* q16  = (u16*)(ws + ((size_t)16 << 20)); // (B,H,T,d)
  u16* k16  = (u16*)(ws + ((size_t)24 << 20)); // (B,H,T,d)
  u16* vt16 = (u16*)(ws + ((size_t)40 << 20)); // (B,H,d,T) written by gemm z==2
  u16* y16  = x16;

  cvt_all<<<8192, 256, 0, stream>>>(x, Wq, Wk, Wv, Wp, x16, w16);
  gemm_bt<0><<<768, 256, 0, stream>>>(x16, w16, bq, bk, bv, (void*)q16, vt16, 4096, 1024, 1024);
  attn_fwd<<<dim3(16, 32), 512, 0, stream>>>(q16, k16, vt16, y16);
  gemm_bt<1><<<256, 256, 0, stream>>>(y16, w16 + 3 * 1048576, bp, bp, bp, d_out, (u16*)nullptr, 4096, 1024, 1024);
}

// Round 27
// 107.385 us; speedup vs baseline: 1.0748x; 1.0748x over previous
//
#include <hip/hip_runtime.h>
#include <hip/hip_bf16.h>
#include <stdint.h>

typedef unsigned short u16;
typedef __attribute__((ext_vector_type(8))) short bf16x8;
typedef __attribute__((ext_vector_type(4))) float f32x4;

#define AS1 __attribute__((address_space(1)))
#define AS3 __attribute__((address_space(3)))

__device__ __forceinline__ void gload_lds16(const void* g, void* l) {
  __builtin_amdgcn_global_load_lds((const AS1 void*)g, (AS3 void*)l, 16, 0, 0);
}

__device__ __forceinline__ u16 f2bf(float f) {
  union { float f; uint32_t u; } v; v.f = f;
  uint32_t r = v.u + 0x7FFFu + ((v.u >> 16) & 1u);
  return (u16)(r >> 16);
}

// ---------------- fp32 -> bf16, all five tensors in ONE launch ----------------
__global__ void cvt_all(const float* __restrict__ x,
                        const float* __restrict__ w0, const float* __restrict__ w1,
                        const float* __restrict__ w2, const float* __restrict__ w3,
                        u16* __restrict__ x16, u16* __restrict__ w16) {
  int i = blockIdx.x * 256 + threadIdx.x;          // float4 index
  const float* src; u16* dst; int off;
  if (i < 1048576) { src = x; dst = x16; off = i; }
  else {
    int j = i - 1048576; int w = j >> 18; off = j & 262143;
    src = (w == 0) ? w0 : (w == 1) ? w1 : (w == 2) ? w2 : w3;
    dst = w16 + (size_t)w * 1048576;
  }
  float4 v = ((const float4*)src)[off];
  uint64_t pk = (uint64_t)f2bf(v.x) | ((uint64_t)f2bf(v.y) << 16) |
                ((uint64_t)f2bf(v.z) << 32) | ((uint64_t)f2bf(v.w) << 48);
  ((uint64_t*)dst)[off] = pk;
}

// ---------------- B^T GEMM: C[m][n] = sum_k A[m][k]*Bw[n][k] + bias[n] ----------------
// BK=64, SINGLE-buffer (dbuf regressed twice: 64KB LDS halves co-residency
// and block-level TLP already hides staging latency -- R24 130us, R26 115us
// vs this structure's 107.6us). XOR-swizzled LDS both sides (R25: fixed the
// measured 10.7M bank-conflict cycles). 1-D grid, bijective XCD swizzle.
// MODE 0: bf16 out; z<2 scatter to (B,H,T,d) via LDS-batched 16B stores
//         (Q scaled 0.125); z==2 writes V transposed to (B,H,d,T) via LDS.
// MODE 1: fp32 out, linear [m][n].
#define BM 128
#define BN 128

template<int MODE>
__global__ __launch_bounds__(256, 2)
void gemm_bt(const u16* __restrict__ A, const u16* __restrict__ Bw,
             const float* __restrict__ bias0, const float* __restrict__ bias1,
             const float* __restrict__ bias2, void* __restrict__ Out,
             u16* __restrict__ VtOut, int M, int N, int K)
{
  __shared__ __align__(16) u16 As[BM * 64];
  __shared__ __align__(16) u16 Bs[BN * 64];
  const int tid = threadIdx.x;
  const int lane = tid & 63, wid = tid >> 6;
  const int lr = lane & 15, lg = lane >> 4;
  const int id = blockIdx.x;
  const int cpx = gridDim.x >> 3;
  const int swz = (id & 7) * cpx + (id >> 3);
  const int z = swz >> 8;                       // 256 tiles per z-slice
  const int rem = swz & 255;
  const int m0 = (rem >> 3) * BM, n0 = (rem & 7) * BN;
  const u16* Bz = Bw + (size_t)z * N * K;
  const float* bias = (MODE == 0) ? (z == 0 ? bias0 : (z == 1 ? bias1 : bias2)) : bias0;
  const int wm = (wid >> 1) * 64, wn = (wid & 1) * 64;
  const int xsl = lr & 7;                       // fragment-read XOR

  f32x4 acc[4][4] = {};

  for (int kt = 0; kt < K; kt += 64) {
    __syncthreads();
#pragma unroll
    for (int i = 0; i < 4; ++i) {
      int cb = (i * 4 + wid) * 64;          // wave-uniform chunk base
      int c = cb + lane;
      int row = c >> 3;
      int kc = ((c & 7) ^ (row & 7)) * 8;   // pre-swizzled source chunk
      gload_lds16(A  + (size_t)(m0 + row) * K + kt + kc, (void*)&As[(size_t)cb * 8]);
      gload_lds16(Bz + (size_t)(n0 + row) * K + kt + kc, (void*)&Bs[(size_t)cb * 8]);
    }
    __syncthreads();

#pragma unroll
    for (int s = 0; s < 2; ++s) {
      bf16x8 af[4], bfr[4];
#pragma unroll
      for (int mf = 0; mf < 4; ++mf)
        af[mf]  = *(const bf16x8*)&As[(wm + mf * 16 + lr) * 64 + (((s * 4 + lg) ^ xsl) * 8)];
#pragma unroll
      for (int nf = 0; nf < 4; ++nf)
        bfr[nf] = *(const bf16x8*)&Bs[(wn + nf * 16 + lr) * 64 + (((s * 4 + lg) ^ xsl) * 8)];
#pragma unroll
      for (int mf = 0; mf < 4; ++mf)
#pragma unroll
        for (int nf = 0; nf < 4; ++nf)
          acc[mf][nf] = __builtin_amdgcn_mfma_f32_16x16x32_bf16(af[mf], bfr[nf], acc[mf][nf], 0, 0, 0);
    }
  }

  if (MODE == 0) {
    __syncthreads();                       // K-loop LDS reads everywhere done
    u16* tb = (wid < 2 ? As : Bs) + (wid & 1) * 4096;   // 8 KB per wave
    if (z == 2) {
      // V epilogue: transpose 64x64 wave quadrant, store (B,H,d,T).
#pragma unroll
      for (int nf = 0; nf < 4; ++nf) {
        float bv = bias[n0 + wn + nf * 16 + lr];
#pragma unroll
        for (int mf = 0; mf < 4; ++mf)
#pragma unroll
          for (int r = 0; r < 4; ++r)
            tb[(nf * 16 + lr) * 64 + (mf * 16 + lg * 4 + r)] = f2bf(acc[mf][nf][r] + bv);
      }
      asm volatile("s_waitcnt lgkmcnt(0)" ::: "memory");  // own-wave writes only
#pragma unroll
      for (int c = 0; c < 8; ++c) {
        int nl = c * 8 + (lane >> 3);        // wave-local n (= d bits)
        int mc = lane & 7;                   // 8-elem m chunk
        bf16x8 vv = *(const bf16x8*)&tb[nl * 64 + mc * 8];
        int ng = n0 + wn + nl;               // global n -> (h,d)
        int mg = m0 + wm + mc * 8;           // global m -> (b,t)
        size_t addr = (((size_t)(mg >> 11) * 16 + (ng >> 6)) * 64 + (ng & 63)) * 2048 + (mg & 2047);
        *(bf16x8*)&VtOut[addr] = vv;
      }
    } else {
      // Q/K epilogue: LDS-batched, d-contiguous 16B stores to (B,H,T,d).
      float qs = (z == 0) ? 0.125f : 1.0f;   // fold 1/sqrt(d) into Q
#pragma unroll
      for (int nf = 0; nf < 4; ++nf) {
        float bv = bias[n0 + wn + nf * 16 + lr];
#pragma unroll
        for (int mf = 0; mf < 4; ++mf)
#pragma unroll
          for (int r = 0; r < 4; ++r)
            tb[(mf * 16 + lg * 4 + r) * 64 + nf * 16 + lr] = f2bf((acc[mf][nf][r] + bv) * qs);
      }
      asm volatile("s_waitcnt lgkmcnt(0)" ::: "memory");  // own-wave writes only
      u16* Oz = (u16*)Out + (size_t)z * 4194304;
#pragma unroll
      for (int c = 0; c < 8; ++c) {
        int ml = c * 8 + (lane >> 3);        // wave-local m
        int nc = lane & 7;                   // 8-elem n (d) chunk
        bf16x8 vv = *(const bf16x8*)&tb[ml * 64 + nc * 8];
        int mg = m0 + wm + ml;               // global m -> (b,t)
        int ng = n0 + wn + nc * 8;           // global n -> (h,d), 8-aligned
        size_t addr = ((size_t)(mg >> 11) * 16 + (ng >> 6)) * (size_t)(2048 * 64)
                    + (size_t)(mg & 2047) * 64 + (ng & 63);
        *(bf16x8*)&Oz[addr] = vv;
      }
    }
    return;
  }

#pragma unroll
  for (int nf = 0; nf < 4; ++nf) {
    float bv = bias[n0 + wn + nf * 16 + lr];
#pragma unroll
    for (int mf = 0; mf < 4; ++mf)
#pragma unroll
      for (int r = 0; r < 4; ++r) {
        int m = m0 + wm + mf * 16 + lg * 4 + r;
        int n = n0 + wn + nf * 16 + lr;
        ((float*)Out)[(size_t)m * N + n] = acc[mf][nf][r] + bv;
      }
  }
}

// ---------------- causal flash attention (R13 exact: best measured 46.5us) ----------------
// grid (16, B*H), 512 thr = 8 waves; block owns 128 q-rows (wave: 16);
// 128-key tiles. Single-buffer LDS + T14 async reg staging; raw barriers.
// Known tradeoff: compiler allocates 64 VGPR and spills ~16 MB/dispatch,
// but beats all clean-allocation variants (R11 54.1, R16 78.2, R18 52.2,
// R19 49.9). expf softmax + manual f2bf.
__global__ __launch_bounds__(512, 4)
void attn_fwd(const u16* __restrict__ q, const u16* __restrict__ k,
              const u16* __restrict__ vt, u16* __restrict__ y)
{
  __shared__ __align__(16) u16 Ks[128 * 64];     // [s][d]  slot = chunk ^ (s&7)
  __shared__ __align__(16) u16 Vs[64 * 128];     // [d][s]  slot = chunk ^ (d&7)
  __shared__ __align__(16) u16 Ps[8][16 * 136];  // per-wave P tile (pad 8)
  const int tid = threadIdx.x, lane = tid & 63, wid = tid >> 6;   // wid 0..7
  const int lr = lane & 15, lg = lane >> 4;
  const int bx = blockIdx.x, by = blockIdx.y;
  const int r4 = (bx + by) & 15;
  const int qt = (by & 16) ? r4 : 15 - r4;       // complementary-pair LPT
  const int q0 = qt * 128;
  const int bh = by;
  const u16* qg = q + (size_t)bh * 2048 * 64;
  const u16* kg = k + (size_t)bh * 2048 * 64;
  const u16* vg = vt + (size_t)bh * 64 * 2048;
  const int trow0 = q0 + wid * 16;
  const int tq = trow0 + lr;

  bf16x8 qa[2];                                   // Q pre-scaled by 0.125 in GEMM
#pragma unroll
  for (int kk = 0; kk < 2; ++kk)
    qa[kk] = *(const bf16x8*)&qg[(size_t)(trow0 + lr) * 64 + kk * 32 + lg * 8];

  // staging split across 8 waves:
  //  K: rows kr0=wid*16+l8 (+8), chunk s8 of 8   -> 2 loads
  //  V: row  vd =wid*8+l8, chunks s8, s8+8 of 16 -> 2 loads
  const int l8 = lane >> 3, s8 = lane & 7;
  const int kr0 = wid * 16 + l8;
  const int vd  = wid * 8 + l8;
  const u16* kld = kg + (size_t)kr0 * 64 + s8 * 8;
  const u16* vld = vg + (size_t)vd * 2048 + s8 * 8;
  u16* kst0 = &Ks[kr0 * 64 + (s8 ^ l8) * 8];           // (kr0+8)&7 == l8 too
  u16* kst1 = &Ks[(kr0 + 8) * 64 + (s8 ^ l8) * 8];
  u16* vst0 = &Vs[vd * 128 + ((s8    ) ^ (vd & 7)) * 8];
  u16* vst1 = &Vs[vd * 128 + ((s8 + 8) ^ (vd & 7)) * 8];

  bf16x8 ldK0, ldK1, ldV0, ldV1;
  ldK0 = *(const bf16x8*)(kld);
  ldK1 = *(const bf16x8*)(kld + 8 * 64);
  ldV0 = *(const bf16x8*)(vld);
  ldV1 = *(const bf16x8*)(vld + 64);

  f32x4 oacc[4] = {};
  float mrun = -1e30f, lrun = 0.f;
  const int nk2 = qt + 1;
  const int xsl = lr & 7;

  for (int j = 0; j < nk2; ++j) {
    // staged regs -> LDS (swizzled), then prefetch next tile
    *(bf16x8*)kst0 = ldK0;  *(bf16x8*)kst1 = ldK1;
    *(bf16x8*)vst0 = ldV0;  *(bf16x8*)vst1 = ldV1;
    if (j + 1 < nk2) {
      const u16* kn = kld + (size_t)(j + 1) * 8192;    // +128 rows
      const u16* vn = vld + (size_t)(j + 1) * 128;     // +128 cols
      ldK0 = *(const bf16x8*)(kn);
      ldK1 = *(const bf16x8*)(kn + 8 * 64);
      ldV0 = *(const bf16x8*)(vn);
      ldV1 = *(const bf16x8*)(vn + 64);
    }
    asm volatile("s_waitcnt lgkmcnt(0)" ::: "memory");   // my ds_writes done
    __builtin_amdgcn_s_barrier();                        // tile visible to all

    // QK^T swapped: sacc[sf][r] = S[s=j*128+sf*16+lg*4+r][t=tq]
    // kb half-batches of 4 keep peak live VGPRs moderate
    f32x4 sacc[8] = {};
#pragma unroll
    for (int kk = 0; kk < 2; ++kk) {
#pragma unroll
      for (int h = 0; h < 2; ++h) {
        bf16x8 kb[4];
#pragma unroll
        for (int sf = 0; sf < 4; ++sf)
          kb[sf] = *(const bf16x8*)&Ks[((h * 4 + sf) * 16 + lr) * 64 + (((kk * 4 + lg) ^ xsl) * 8)];
#pragma unroll
        for (int sf = 0; sf < 4; ++sf)
          sacc[h * 4 + sf] = __builtin_amdgcn_mfma_f32_16x16x32_bf16(kb[sf], qa[kk], sacc[h * 4 + sf], 0, 0, 0);
      }
    }

    if (j == qt) {                      // diagonal tile: mask s > t
#pragma unroll
      for (int sf = 0; sf < 8; ++sf)
#pragma unroll
        for (int r = 0; r < 4; ++r) {
          int s = j * 128 + sf * 16 + lg * 4 + r;
          if (s > tq) sacc[sf][r] = -1e30f;
        }
    }

    // online softmax for row tq: in-register tree max + 2-step lg reduce
    float m01 = fmaxf(fmaxf(fmaxf(sacc[0][0], sacc[0][1]), fmaxf(sacc[0][2], sacc[0][3])),
                      fmaxf(fmaxf(sacc[1][0], sacc[1][1]), fmaxf(sacc[1][2], sacc[1][3])));
    float m23 = fmaxf(fmaxf(fmaxf(sacc[2][0], sacc[2][1]), fmaxf(sacc[2][2], sacc[2][3])),
                      fmaxf(fmaxf(sacc[3][0], sacc[3][1]), fmaxf(sacc[3][2], sacc[3][3])));
    float m45 = fmaxf(fmaxf(fmaxf(sacc[4][0], sacc[4][1]), fmaxf(sacc[4][2], sacc[4][3])),
                      fmaxf(fmaxf(sacc[5][0], sacc[5][1]), fmaxf(sacc[5][2], sacc[5][3])));
    float m67 = fmaxf(fmaxf(fmaxf(sacc[6][0], sacc[6][1]), fmaxf(sacc[6][2], sacc[6][3])),
                      fmaxf(fmaxf(sacc[7][0], sacc[7][1]), fmaxf(sacc[7][2], sacc[7][3])));
    float mx = fmaxf(fmaxf(m01, m23), fmaxf(m45, m67));
    mx = fmaxf(mx, __shfl_xor(mx, 16));
    mx = fmaxf(mx, __shfl_xor(mx, 32));
    if (!__all(mx - mrun <= 8.0f)) {    // T13: rescale only when max moved
      float mn = fmaxf(mrun, mx);
      float scn = __expf(mrun - mn);
      mrun = mn;
      lrun *= scn;
      float scr[4];
#pragma unroll
      for (int r = 0; r < 4; ++r) scr[r] = __shfl(scn, lg * 4 + r);
#pragma unroll
      for (int nf = 0; nf < 4; ++nf)
#pragma unroll
        for (int r = 0; r < 4; ++r) oacc[nf][r] *= scr[r];
    }
    float rs = 0.f;
#pragma unroll
    for (int sf = 0; sf < 8; ++sf)
#pragma unroll
      for (int r = 0; r < 4; ++r) {
        float p = __expf(sacc[sf][r] - mrun);
        sacc[sf][r] = p;
        rs += p;
      }
    rs += __shfl_xor(rs, 16);
    rs += __shfl_xor(rs, 32);
    lrun += rs;

    // P -> LDS (wave-private): row t=lr, cols sf*16+lg*4+{0..3}
#pragma unroll
    for (int sf = 0; sf < 8; ++sf) {
      union { ushort4 u; uint2 d; } pk_;
      pk_.u.x = f2bf(sacc[sf][0]); pk_.u.y = f2bf(sacc[sf][1]);
      pk_.u.z = f2bf(sacc[sf][2]); pk_.u.w = f2bf(sacc[sf][3]);
      *(uint2*)&Ps[wid][lr * 136 + sf * 16 + lg * 4] = pk_.d;
    }

    // PV: O[t][n] += P[t][s] * Vt[n][s], s over 128 keys (kk 0..3)
#pragma unroll
    for (int kk = 0; kk < 4; ++kk) {
      bf16x8 pa = *(const bf16x8*)&Ps[wid][lr * 136 + kk * 32 + lg * 8];
      bf16x8 vb[4];
#pragma unroll
      for (int nf = 0; nf < 4; ++nf)
        vb[nf] = *(const bf16x8*)&Vs[(nf * 16 + lr) * 128 + (((kk * 4 + lg) ^ xsl) * 8)];
#pragma unroll
      for (int nf = 0; nf < 4; ++nf)
        oacc[nf] = __builtin_amdgcn_mfma_f32_16x16x32_bf16(pa, vb[nf], oacc[nf], 0, 0, 0);
    }

    asm volatile("s_waitcnt lgkmcnt(0)" ::: "memory");   // my K/V reads retired
    __builtin_amdgcn_s_barrier();                        // safe to overwrite
  }

  const int b = bh >> 4, h = bh & 15;
#pragma unroll
  for (int r = 0; r < 4; ++r) {
    float lshf = __shfl(lrun, lg * 4 + r);
    float inv = 1.f / lshf;
    int t = trow0 + lg * 4 + r;
#pragma unroll
    for (int nf = 0; nf < 4; ++nf) {
      int n = nf * 16 + lr;
      y[((size_t)b * 2048 + t) * 1024 + h * 64 + n] = f2bf(oacc[nf][r] * inv);
    }
  }
}

extern "C" void kernel_launch(void* const* d_in, const int* in_sizes, int n_in,
                              void* d_out, int out_size, void* d_ws, size_t ws_size,
                              hipStream_t stream) {
  const float* x  = (const float*)d_in[0];
  const float* Wq = (const float*)d_in[1];
  const float* bq = (const float*)d_in[2];
  const float* Wk = (const float*)d_in[3];
  const float* bk = (const float*)d_in[4];
  const float* Wv = (const float*)d_in[5];
  const float* bv = (const float*)d_in[6];
  const float* Wp = (const float*)d_in[7];
  const float* bp = (const float*)d_in[8];

  char* ws = (char*)d_ws;
  u16* x16  = (u16*)(ws + (size_t)0);          // 4096x1024 bf16 (reused as y16 later)
  u16* w16  = (u16*)(ws + ((size_t)8  << 20)); // Wq,Wk,Wv,Wp bf16, 1M elems each
  u16* q16  = (u16*)(ws + ((size_t)16 << 20)); // (B,H,T,d)
  u16* k16  = (u16*)(ws + ((size_t)24 << 20)); // (B,H,T,d)
  u16* vt16 = (u16*)(ws + ((size_t)40 << 20)); // (B,H,d,T) written by gemm z==2
  u16* y16  = x16;

  cvt_all<<<8192, 256, 0, stream>>>(x, Wq, Wk, Wv, Wp, x16, w16);
  gemm_bt<0><<<768, 256, 0, stream>>>(x16, w16, bq, bk, bv, (void*)q16, vt16, 4096, 1024, 1024);
  attn_fwd<<<dim3(16, 32), 512, 0, stream>>>(q16, k16, vt16, y16);
  gemm_bt<1><<<256, 256, 0, stream>>>(y16, w16 + 3 * 1048576, bp, bp, bp, d_out, (u16*)nullptr, 4096, 1024, 1024);
}

// Round 28
// 104.336 us; speedup vs baseline: 1.1062x; 1.0292x over previous
//
#include <hip/hip_runtime.h>
#include <hip/hip_bf16.h>
#include <stdint.h>

typedef unsigned short u16;
typedef __attribute__((ext_vector_type(8))) short bf16x8;
typedef __attribute__((ext_vector_type(4))) float f32x4;

#define AS1 __attribute__((address_space(1)))
#define AS3 __attribute__((address_space(3)))

__device__ __forceinline__ void gload_lds16(const void* g, void* l) {
  __builtin_amdgcn_global_load_lds((const AS1 void*)g, (AS3 void*)l, 16, 0, 0);
}

__device__ __forceinline__ u16 f2bf(float f) {
  union { float f; uint32_t u; } v; v.f = f;
  uint32_t r = v.u + 0x7FFFu + ((v.u >> 16) & 1u);
  return (u16)(r >> 16);
}

// ---------------- fp32 -> bf16, all five tensors in ONE launch ----------------
__global__ void cvt_all(const float* __restrict__ x,
                        const float* __restrict__ w0, const float* __restrict__ w1,
                        const float* __restrict__ w2, const float* __restrict__ w3,
                        u16* __restrict__ x16, u16* __restrict__ w16) {
  int i = blockIdx.x * 256 + threadIdx.x;          // float4 index
  const float* src; u16* dst; int off;
  if (i < 1048576) { src = x; dst = x16; off = i; }
  else {
    int j = i - 1048576; int w = j >> 18; off = j & 262143;
    src = (w == 0) ? w0 : (w == 1) ? w1 : (w == 2) ? w2 : w3;
    dst = w16 + (size_t)w * 1048576;
  }
  float4 v = ((const float4*)src)[off];
  uint64_t pk = (uint64_t)f2bf(v.x) | ((uint64_t)f2bf(v.y) << 16) |
                ((uint64_t)f2bf(v.z) << 32) | ((uint64_t)f2bf(v.w) << 48);
  ((uint64_t*)dst)[off] = pk;
}

// ---------------- B^T GEMM: C[m][n] = sum_k A[m][k]*Bw[n][k] + bias[n] ----------------
// BK=64, SINGLE-buffer (dbuf regressed twice: LDS halves co-residency and
// block-level TLP already hides staging latency). XOR-swizzled LDS both
// sides (R25: fixed measured 10.7M bank-conflict cycles). 1-D grid,
// bijective XCD swizzle (T1).
// MODE 0: 128x128 tiles; bf16 out; z<2 scatter to (B,H,T,d) via LDS-batched
//         16B stores (Q scaled 0.125); z==2 writes V transposed (B,H,d,T).
// MODE 1: 64x128 tiles (512 blocks = 2/CU co-residency; R27 showed 256
//         blocks = 1/CU leaves staging latency unhidden); fp32 out linear.
#define BM 128
#define BN 128

template<int MODE>
__global__ __launch_bounds__(256, 2)
void gemm_bt(const u16* __restrict__ A, const u16* __restrict__ Bw,
             const float* __restrict__ bias0, const float* __restrict__ bias1,
             const float* __restrict__ bias2, void* __restrict__ Out,
             u16* __restrict__ VtOut, int M, int N, int K)
{
  constexpr int TBM = (MODE == 0) ? 128 : 64;   // tile M
  constexpr int MF  = TBM / 32;                 // m fragments per wave (4 / 2)
  __shared__ __align__(16) u16 As[TBM * 64];
  __shared__ __align__(16) u16 Bs[BN * 64];
  const int tid = threadIdx.x;
  const int lane = tid & 63, wid = tid >> 6;
  const int lr = lane & 15, lg = lane >> 4;
  const int id = blockIdx.x;
  const int cpx = gridDim.x >> 3;
  const int swz = (id & 7) * cpx + (id >> 3);
  int z, m0, n0;
  if (MODE == 0) {
    z = swz >> 8;                               // 256 tiles per z-slice
    int rem = swz & 255;
    m0 = (rem >> 3) * 128; n0 = (rem & 7) * 128;
  } else {
    z = 0;
    m0 = (swz >> 3) * 64;  n0 = (swz & 7) * 128;
  }
  const u16* Bz = Bw + (size_t)z * N * K;
  const float* bias = (MODE == 0) ? (z == 0 ? bias0 : (z == 1 ? bias1 : bias2)) : bias0;
  const int wm = (wid >> 1) * (TBM / 2), wn = (wid & 1) * 64;
  const int xsl = lr & 7;                       // fragment-read XOR

  f32x4 acc[MF][4] = {};

  for (int kt = 0; kt < K; kt += 64) {
    __syncthreads();
#pragma unroll
    for (int i = 0; i < MF; ++i) {            // A: TBM rows, 32 rows/iter
      int cb = (i * 4 + wid) * 64;
      int c = cb + lane;
      int row = c >> 3;
      int kc = ((c & 7) ^ (row & 7)) * 8;     // pre-swizzled source chunk
      gload_lds16(A + (size_t)(m0 + row) * K + kt + kc, (void*)&As[(size_t)cb * 8]);
    }
#pragma unroll
    for (int i = 0; i < 4; ++i) {             // B: 128 rows
      int cb = (i * 4 + wid) * 64;
      int c = cb + lane;
      int row = c >> 3;
      int kc = ((c & 7) ^ (row & 7)) * 8;
      gload_lds16(Bz + (size_t)(n0 + row) * K + kt + kc, (void*)&Bs[(size_t)cb * 8]);
    }
    __syncthreads();

#pragma unroll
    for (int s = 0; s < 2; ++s) {
      bf16x8 af[MF], bfr[4];
#pragma unroll
      for (int mf = 0; mf < MF; ++mf)
        af[mf]  = *(const bf16x8*)&As[(wm + mf * 16 + lr) * 64 + (((s * 4 + lg) ^ xsl) * 8)];
#pragma unroll
      for (int nf = 0; nf < 4; ++nf)
        bfr[nf] = *(const bf16x8*)&Bs[(wn + nf * 16 + lr) * 64 + (((s * 4 + lg) ^ xsl) * 8)];
#pragma unroll
      for (int mf = 0; mf < MF; ++mf)
#pragma unroll
        for (int nf = 0; nf < 4; ++nf)
          acc[mf][nf] = __builtin_amdgcn_mfma_f32_16x16x32_bf16(af[mf], bfr[nf], acc[mf][nf], 0, 0, 0);
    }
  }

  if (MODE == 0) {
    __syncthreads();                       // K-loop LDS reads everywhere done
    u16* tb = (wid < 2 ? As : Bs) + (wid & 1) * 4096;   // 8 KB per wave
    if (z == 2) {
      // V epilogue: transpose 64x64 wave quadrant, store (B,H,d,T).
#pragma unroll
      for (int nf = 0; nf < 4; ++nf) {
        float bv = bias[n0 + wn + nf * 16 + lr];
#pragma unroll
        for (int mf = 0; mf < 4; ++mf)
#pragma unroll
          for (int r = 0; r < 4; ++r)
            tb[(nf * 16 + lr) * 64 + (mf * 16 + lg * 4 + r)] = f2bf(acc[mf][nf][r] + bv);
      }
      asm volatile("s_waitcnt lgkmcnt(0)" ::: "memory");  // own-wave writes only
#pragma unroll
      for (int c = 0; c < 8; ++c) {
        int nl = c * 8 + (lane >> 3);        // wave-local n (= d bits)
        int mc = lane & 7;                   // 8-elem m chunk
        bf16x8 vv = *(const bf16x8*)&tb[nl * 64 + mc * 8];
        int ng = n0 + wn + nl;               // global n -> (h,d)
        int mg = m0 + wm + mc * 8;           // global m -> (b,t)
        size_t addr = (((size_t)(mg >> 11) * 16 + (ng >> 6)) * 64 + (ng & 63)) * 2048 + (mg & 2047);
        *(bf16x8*)&VtOut[addr] = vv;
      }
    } else {
      // Q/K epilogue: LDS-batched, d-contiguous 16B stores to (B,H,T,d).
      float qs = (z == 0) ? 0.125f : 1.0f;   // fold 1/sqrt(d) into Q
#pragma unroll
      for (int nf = 0; nf < 4; ++nf) {
        float bv = bias[n0 + wn + nf * 16 + lr];
#pragma unroll
        for (int mf = 0; mf < 4; ++mf)
#pragma unroll
          for (int r = 0; r < 4; ++r)
            tb[(mf * 16 + lg * 4 + r) * 64 + nf * 16 + lr] = f2bf((acc[mf][nf][r] + bv) * qs);
      }
      asm volatile("s_waitcnt lgkmcnt(0)" ::: "memory");  // own-wave writes only
      u16* Oz = (u16*)Out + (size_t)z * 4194304;
#pragma unroll
      for (int c = 0; c < 8; ++c) {
        int ml = c * 8 + (lane >> 3);        // wave-local m
        int nc = lane & 7;                   // 8-elem n (d) chunk
        bf16x8 vv = *(const bf16x8*)&tb[ml * 64 + nc * 8];
        int mg = m0 + wm + ml;               // global m -> (b,t)
        int ng = n0 + wn + nc * 8;           // global n -> (h,d), 8-aligned
        size_t addr = ((size_t)(mg >> 11) * 16 + (ng >> 6)) * (size_t)(2048 * 64)
                    + (size_t)(mg & 2047) * 64 + (ng & 63);
        *(bf16x8*)&Oz[addr] = vv;
      }
    }
    return;
  }

#pragma unroll
  for (int nf = 0; nf < 4; ++nf) {
    float bv = bias[n0 + wn + nf * 16 + lr];
#pragma unroll
    for (int mf = 0; mf < MF; ++mf)
#pragma unroll
      for (int r = 0; r < 4; ++r) {
        int m = m0 + wm + mf * 16 + lg * 4 + r;
        int n = n0 + wn + nf * 16 + lr;
        ((float*)Out)[(size_t)m * N + n] = acc[mf][nf][r] + bv;
      }
  }
}

// ---------------- causal flash attention (R13 exact: best measured 46.5us) ----------------
// grid (16, B*H), 512 thr = 8 waves; block owns 128 q-rows (wave: 16);
// 128-key tiles. Single-buffer LDS + T14 async reg staging; raw barriers.
// Known tradeoff: compiler allocates 64 VGPR and spills ~16 MB/dispatch,
// but beats all clean-allocation variants (R11 54.1, R16 78.2, R18 52.2,
// R19 49.9). expf softmax + manual f2bf.
__global__ __launch_bounds__(512, 4)
void attn_fwd(const u16* __restrict__ q, const u16* __restrict__ k,
              const u16* __restrict__ vt, u16* __restrict__ y)
{
  __shared__ __align__(16) u16 Ks[128 * 64];     // [s][d]  slot = chunk ^ (s&7)
  __shared__ __align__(16) u16 Vs[64 * 128];     // [d][s]  slot = chunk ^ (d&7)
  __shared__ __align__(16) u16 Ps[8][16 * 136];  // per-wave P tile (pad 8)
  const int tid = threadIdx.x, lane = tid & 63, wid = tid >> 6;   // wid 0..7
  const int lr = lane & 15, lg = lane >> 4;
  const int bx = blockIdx.x, by = blockIdx.y;
  const int r4 = (bx + by) & 15;
  const int qt = (by & 16) ? r4 : 15 - r4;       // complementary-pair LPT
  const int q0 = qt * 128;
  const int bh = by;
  const u16* qg = q + (size_t)bh * 2048 * 64;
  const u16* kg = k + (size_t)bh * 2048 * 64;
  const u16* vg = vt + (size_t)bh * 64 * 2048;
  const int trow0 = q0 + wid * 16;
  const int tq = trow0 + lr;

  bf16x8 qa[2];                                   // Q pre-scaled by 0.125 in GEMM
#pragma unroll
  for (int kk = 0; kk < 2; ++kk)
    qa[kk] = *(const bf16x8*)&qg[(size_t)(trow0 + lr) * 64 + kk * 32 + lg * 8];

  // staging split across 8 waves:
  //  K: rows kr0=wid*16+l8 (+8), chunk s8 of 8   -> 2 loads
  //  V: row  vd =wid*8+l8, chunks s8, s8+8 of 16 -> 2 loads
  const int l8 = lane >> 3, s8 = lane & 7;
  const int kr0 = wid * 16 + l8;
  const int vd  = wid * 8 + l8;
  const u16* kld = kg + (size_t)kr0 * 64 + s8 * 8;
  const u16* vld = vg + (size_t)vd * 2048 + s8 * 8;
  u16* kst0 = &Ks[kr0 * 64 + (s8 ^ l8) * 8];           // (kr0+8)&7 == l8 too
  u16* kst1 = &Ks[(kr0 + 8) * 64 + (s8 ^ l8) * 8];
  u16* vst0 = &Vs[vd * 128 + ((s8    ) ^ (vd & 7)) * 8];
  u16* vst1 = &Vs[vd * 128 + ((s8 + 8) ^ (vd & 7)) * 8];

  bf16x8 ldK0, ldK1, ldV0, ldV1;
  ldK0 = *(const bf16x8*)(kld);
  ldK1 = *(const bf16x8*)(kld + 8 * 64);
  ldV0 = *(const bf16x8*)(vld);
  ldV1 = *(const bf16x8*)(vld + 64);

  f32x4 oacc[4] = {};
  float mrun = -1e30f, lrun = 0.f;
  const int nk2 = qt + 1;
  const int xsl = lr & 7;

  for (int j = 0; j < nk2; ++j) {
    // staged regs -> LDS (swizzled), then prefetch next tile
    *(bf16x8*)kst0 = ldK0;  *(bf16x8*)kst1 = ldK1;
    *(bf16x8*)vst0 = ldV0;  *(bf16x8*)vst1 = ldV1;
    if (j + 1 < nk2) {
      const u16* kn = kld + (size_t)(j + 1) * 8192;    // +128 rows
      const u16* vn = vld + (size_t)(j + 1) * 128;     // +128 cols
      ldK0 = *(const bf16x8*)(kn);
      ldK1 = *(const bf16x8*)(kn + 8 * 64);
      ldV0 = *(const bf16x8*)(vn);
      ldV1 = *(const bf16x8*)(vn + 64);
    }
    asm volatile("s_waitcnt lgkmcnt(0)" ::: "memory");   // my ds_writes done
    __builtin_amdgcn_s_barrier();                        // tile visible to all

    // QK^T swapped: sacc[sf][r] = S[s=j*128+sf*16+lg*4+r][t=tq]
    // kb half-batches of 4 keep peak live VGPRs moderate
    f32x4 sacc[8] = {};
#pragma unroll
    for (int kk = 0; kk < 2; ++kk) {
#pragma unroll
      for (int h = 0; h < 2; ++h) {
        bf16x8 kb[4];
#pragma unroll
        for (int sf = 0; sf < 4; ++sf)
          kb[sf] = *(const bf16x8*)&Ks[((h * 4 + sf) * 16 + lr) * 64 + (((kk * 4 + lg) ^ xsl) * 8)];
#pragma unroll
        for (int sf = 0; sf < 4; ++sf)
          sacc[h * 4 + sf] = __builtin_amdgcn_mfma_f32_16x16x32_bf16(kb[sf], qa[kk], sacc[h * 4 + sf], 0, 0, 0);
      }
    }

    if (j == qt) {                      // diagonal tile: mask s > t
#pragma unroll
      for (int sf = 0; sf < 8; ++sf)
#pragma unroll
        for (int r = 0; r < 4; ++r) {
          int s = j * 128 + sf * 16 + lg * 4 + r;
          if (s > tq) sacc[sf][r] = -1e30f;
        }
    }

    // online softmax for row tq: in-register tree max + 2-step lg reduce
    float m01 = fmaxf(fmaxf(fmaxf(sacc[0][0], sacc[0][1]), fmaxf(sacc[0][2], sacc[0][3])),
                      fmaxf(fmaxf(sacc[1][0], sacc[1][1]), fmaxf(sacc[1][2], sacc[1][3])));
    float m23 = fmaxf(fmaxf(fmaxf(sacc[2][0], sacc[2][1]), fmaxf(sacc[2][2], sacc[2][3])),
                      fmaxf(fmaxf(sacc[3][0], sacc[3][1]), fmaxf(sacc[3][2], sacc[3][3])));
    float m45 = fmaxf(fmaxf(fmaxf(sacc[4][0], sacc[4][1]), fmaxf(sacc[4][2], sacc[4][3])),
                      fmaxf(fmaxf(sacc[5][0], sacc[5][1]), fmaxf(sacc[5][2], sacc[5][3])));
    float m67 = fmaxf(fmaxf(fmaxf(sacc[6][0], sacc[6][1]), fmaxf(sacc[6][2], sacc[6][3])),
                      fmaxf(fmaxf(sacc[7][0], sacc[7][1]), fmaxf(sacc[7][2], sacc[7][3])));
    float mx = fmaxf(fmaxf(m01, m23), fmaxf(m45, m67));
    mx = fmaxf(mx, __shfl_xor(mx, 16));
    mx = fmaxf(mx, __shfl_xor(mx, 32));
    if (!__all(mx - mrun <= 8.0f)) {    // T13: rescale only when max moved
      float mn = fmaxf(mrun, mx);
      float scn = __expf(mrun - mn);
      mrun = mn;
      lrun *= scn;
      float scr[4];
#pragma unroll
      for (int r = 0; r < 4; ++r) scr[r] = __shfl(scn, lg * 4 + r);
#pragma unroll
      for (int nf = 0; nf < 4; ++nf)
#pragma unroll
        for (int r = 0; r < 4; ++r) oacc[nf][r] *= scr[r];
    }
    float rs = 0.f;
#pragma unroll
    for (int sf = 0; sf < 8; ++sf)
#pragma unroll
      for (int r = 0; r < 4; ++r) {
        float p = __expf(sacc[sf][r] - mrun);
        sacc[sf][r] = p;
        rs += p;
      }
    rs += __shfl_xor(rs, 16);
    rs += __shfl_xor(rs, 32);
    lrun += rs;

    // P -> LDS (wave-private): row t=lr, cols sf*16+lg*4+{0..3}
#pragma unroll
    for (int sf = 0; sf < 8; ++sf) {
      union { ushort4 u; uint2 d; } pk_;
      pk_.u.x = f2bf(sacc[sf][0]); pk_.u.y = f2bf(sacc[sf][1]);
      pk_.u.z = f2bf(sacc[sf][2]); pk_.u.w = f2bf(sacc[sf][3]);
      *(uint2*)&Ps[wid][lr * 136 + sf * 16 + lg * 4] = pk_.d;
    }

    // PV: O[t][n] += P[t][s] * Vt[n][s], s over 128 keys (kk 0..3)
#pragma unroll
    for (int kk = 0; kk < 4; ++kk) {
      bf16x8 pa = *(const bf16x8*)&Ps[wid][lr * 136 + kk * 32 + lg * 8];
      bf16x8 vb[4];
#pragma unroll
      for (int nf = 0; nf < 4; ++nf)
        vb[nf] = *(const bf16x8*)&Vs[(nf * 16 + lr) * 128 + (((kk * 4 + lg) ^ xsl) * 8)];
#pragma unroll
      for (int nf = 0; nf < 4; ++nf)
        oacc[nf] = __builtin_amdgcn_mfma_f32_16x16x32_bf16(pa, vb[nf], oacc[nf], 0, 0, 0);
    }

    asm volatile("s_waitcnt lgkmcnt(0)" ::: "memory");   // my K/V reads retired
    __builtin_amdgcn_s_barrier();                        // safe to overwrite
  }

  const int b = bh >> 4, h = bh & 15;
#pragma unroll
  for (int r = 0; r < 4; ++r) {
    float lshf = __shfl(lrun, lg * 4 + r);
    float inv = 1.f / lshf;
    int t = trow0 + lg * 4 + r;
#pragma unroll
    for (int nf = 0; nf < 4; ++nf) {
      int n = nf * 16 + lr;
      y[((size_t)b * 2048 + t) * 1024 + h * 64 + n] = f2bf(oacc[nf][r] * inv);
    }
  }
}

extern "C" void kernel_launch(void* const* d_in, const int* in_sizes, int n_in,
                              void* d_out, int out_size, void* d_ws, size_t ws_size,
                              hipStream_t stream) {
  const float* x  = (const float*)d_in[0];
  const float* Wq = (const float*)d_in[1];
  const float* bq = (const float*)d_in[2];
  const float* Wk = (const float*)d_in[3];
  const float* bk = (const float*)d_in[4];
  const float* Wv = (const float*)d_in[5];
  const float* bv = (const float*)d_in[6];
  const float* Wp = (const float*)d_in[7];
  const float* bp = (const float*)d_in[8];

  char* ws = (char*)d_ws;
  u16* x16  = (u16*)(ws + (size_t)0);          // 4096x1024 bf16 (reused as y16 later)
  u16* w16  = (u16*)(ws + ((size_t)8  << 20)); // Wq,Wk,Wv,Wp bf16, 1M elems each
  u16* q16  = (u16*)(ws + ((size_t)16 << 20)); // (B,H,T,d)
  u16* k16  = (u16*)(ws + ((size_t)24 << 20)); // (B,H,T,d)
  u16* vt16 = (u16*)(ws + ((size_t)40 << 20)); // (B,H,d,T) written by gemm z==2
  u16* y16  = x16;

  cvt_all<<<8192, 256, 0, stream>>>(x, Wq, Wk, Wv, Wp, x16, w16);
  gemm_bt<0><<<768, 256, 0, stream>>>(x16, w16, bq, bk, bv, (void*)q16, vt16, 4096, 1024, 1024);
  attn_fwd<<<dim3(16, 32), 512, 0, stream>>>(q16, k16, vt16, y16);
  gemm_bt<1><<<512, 256, 0, stream>>>(y16, w16 + 3 * 1048576, bp, bp, bp, d_out, (u16*)nullptr, 4096, 1024, 1024);
}